// Round 1
// baseline (370.558 us; speedup 1.0000x reference)
//
#include <hip/hip_runtime.h>
#include <hip/hip_bf16.h>

#define EPS_Z 1e-4f

typedef __attribute__((ext_vector_type(8))) short bf16x8;
typedef __attribute__((ext_vector_type(4))) float f32x4;

__device__ __forceinline__ float b2f(short s) {
    union { unsigned u; float f; } cv;
    cv.u = ((unsigned)(unsigned short)s) << 16;
    return cv.f;
}

__device__ __forceinline__ void gld_lds16(const __hip_bfloat16* g, __hip_bfloat16* l) {
    __builtin_amdgcn_global_load_lds(
        (__attribute__((address_space(1))) void*)(g),
        (__attribute__((address_space(3))) void*)(l),
        16, 0, 0);
}

// Raw workgroup barrier that is ALSO a compiler memory fence + scheduling wall.
// (s_barrier alone does not stop LLVM from moving LDS loads across it.)
__device__ __forceinline__ void fence_barrier() {
    asm volatile("" ::: "memory");
    __builtin_amdgcn_sched_barrier(0);
    __builtin_amdgcn_s_barrier();
    __builtin_amdgcn_sched_barrier(0);
    asm volatile("" ::: "memory");
}

// fp32 -> bf16 (RNE), 4 elems/thread
__global__ __launch_bounds__(256)
void cvt_f32_bf16(const float* __restrict__ in, __hip_bfloat16* __restrict__ out, int n4)
{
    int i = blockIdx.x * 256 + threadIdx.x;
    if (i >= n4) return;
    float4 v = ((const float4*)in)[i];
    union { short4 s; __hip_bfloat16 h[4]; } o;
    o.h[0] = __float2bfloat16(v.x);
    o.h[1] = __float2bfloat16(v.y);
    o.h[2] = __float2bfloat16(v.z);
    o.h[3] = __float2bfloat16(v.w);
    ((short4*)out)[i] = o.s;
}

// ============================================================================
// 256x256 / BK=64 / 8-wave / 8-phase GEMM (T1+T2+T3+T4+T5), MODE-1 epilogue:
// C[M,N] = A[M,K] @ B[N,K]^T, relu on cols<1536, bf16 out.
// Schedule (per K-tile t, buf=t&1, 4 phases):
//   ph0: ds_read B(all 8) + A(m0,m1); stage (t+1).A0 -> buf^1
//   ph1: ds_read A(m2,m3);            stage (t+1).A1 -> buf^1
//   ph2: ds_read A(m4,m5);            stage (t+2).B0 -> buf   (B freed at ph0)
//   ph3: ds_read A(m6,m7);            stage (t+2).B1 -> buf
//   each phase: reads|stage -> barrier -> lgkmcnt(0) -> setprio(1) 16xMFMA -> barrier
//   tile boundary: vmcnt(4)  (all of tile t+1 retired; t+2's B halves stay in flight)
// ============================================================================
__global__ __launch_bounds__(512, 2)
void gemm256_relu(const __hip_bfloat16* __restrict__ A,
                  const __hip_bfloat16* __restrict__ B,
                  __hip_bfloat16* __restrict__ C,
                  int K, int N, int gx)
{
    __shared__ __align__(16) __hip_bfloat16 As[2][256 * 64];
    __shared__ __align__(16) __hip_bfloat16 Bs[2][256 * 64];

    // bijective XCD swizzle (nwg % 8 != 0 safe, m204)
    const int nwg = (int)gridDim.x;
    const int g = blockIdx.x;
    const int xcd = g & 7, lin = g >> 3;
    const int q = nwg >> 3, r = nwg & 7;
    const int gp = (xcd < r ? xcd * (q + 1) : r * (q + 1) + (xcd - r) * q) + lin;
    const int bx = gp % gx, by = gp / gx;

    const int tid = threadIdx.x;
    const int w = tid >> 6, l = tid & 63;
    const int l15 = l & 15, lq = l >> 4;
    const int rx = l15 & 7;
    const int wr = (w >> 2) * 128;     // 2 waves in M
    const int wc = (w & 3) * 64;       // 4 waves in N
    const int srow8 = l >> 3;
    const int scol = ((l & 7) ^ srow8) << 3;   // pre-swizzled global col-chunk

    const __hip_bfloat16* Ab = A + (size_t)by * 256 * K;
    const __hip_bfloat16* Bb = B + (size_t)bx * 256 * K;

    f32x4 acc[8][4] = {};
    const int NT = K >> 6;   // 12 for K=768

// stage one 128-row half (16 chunks of 8 rows); 2 global_load_lds x16B per thread
#define STAGE_A(buf_, half_, t_) do { \
    const int k0_ = (t_) << 6; \
    const int c0_ = (half_) * 16 + w * 2; \
    gld_lds16(Ab + (size_t)(c0_ * 8 + srow8) * K + (k0_ + scol), &As[buf_][c0_ * 512]); \
    gld_lds16(Ab + (size_t)((c0_ + 1) * 8 + srow8) * K + (k0_ + scol), &As[buf_][(c0_ + 1) * 512]); \
} while (0)
#define STAGE_B(buf_, half_, t_) do { \
    const int k0_ = (t_) << 6; \
    const int c0_ = (half_) * 16 + w * 2; \
    gld_lds16(Bb + (size_t)(c0_ * 8 + srow8) * K + (k0_ + scol), &Bs[buf_][c0_ * 512]); \
    gld_lds16(Bb + (size_t)((c0_ + 1) * 8 + srow8) * K + (k0_ + scol), &Bs[buf_][(c0_ + 1) * 512]); \
} while (0)

    // prologue: tile0 fully (B then A), tile1's B halves. 12 loads in flight,
    // wait until <=4 (i.e. all 8 of tile0 retired; tile1.B may fly).
    STAGE_B(0, 0, 0); STAGE_B(0, 1, 0);
    STAGE_A(0, 0, 0); STAGE_A(0, 1, 0);
    STAGE_B(1, 0, 1); STAGE_B(1, 1, 1);
    asm volatile("s_waitcnt vmcnt(4)" ::: "memory");
    fence_barrier();

    for (int t = 0; t < NT; ++t) {
        const int buf = t & 1;
        const __hip_bfloat16* Asb = As[buf];
        const __hip_bfloat16* Bsb = Bs[buf];
        bf16x8 bfr[4][2];
        bf16x8 afr[2][2];

        // ================= phase 0: B all + A(m0,m1); stage (t+1).A0 ========
        #pragma unroll
        for (int j = 0; j < 4; ++j)
            #pragma unroll
            for (int ks = 0; ks < 2; ++ks)
                bfr[j][ks] = *(const bf16x8*)(Bsb + (wc + j * 16 + l15) * 64 + (((ks * 4 + lq) ^ rx) << 3));
        #pragma unroll
        for (int d = 0; d < 2; ++d)
            #pragma unroll
            for (int ks = 0; ks < 2; ++ks)
                afr[d][ks] = *(const bf16x8*)(Asb + (wr + (0 + d) * 16 + l15) * 64 + (((ks * 4 + lq) ^ rx) << 3));
        if (t + 1 < NT) STAGE_A(buf ^ 1, 0, t + 1);
        fence_barrier();
        asm volatile("s_waitcnt lgkmcnt(0)" ::: "memory");
        __builtin_amdgcn_sched_barrier(0);
        __builtin_amdgcn_s_setprio(1);
        #pragma unroll
        for (int d = 0; d < 2; ++d)
            #pragma unroll
            for (int j = 0; j < 4; ++j)
                #pragma unroll
                for (int ks = 0; ks < 2; ++ks)
                    acc[0 + d][j] = __builtin_amdgcn_mfma_f32_16x16x32_bf16(afr[d][ks], bfr[j][ks], acc[0 + d][j], 0, 0, 0);
        __builtin_amdgcn_s_setprio(0);
        fence_barrier();

        // ================= phase 1: A(m2,m3); stage (t+1).A1 ================
        #pragma unroll
        for (int d = 0; d < 2; ++d)
            #pragma unroll
            for (int ks = 0; ks < 2; ++ks)
                afr[d][ks] = *(const bf16x8*)(Asb + (wr + (2 + d) * 16 + l15) * 64 + (((ks * 4 + lq) ^ rx) << 3));
        if (t + 1 < NT) STAGE_A(buf ^ 1, 1, t + 1);
        fence_barrier();
        asm volatile("s_waitcnt lgkmcnt(0)" ::: "memory");
        __builtin_amdgcn_sched_barrier(0);
        __builtin_amdgcn_s_setprio(1);
        #pragma unroll
        for (int d = 0; d < 2; ++d)
            #pragma unroll
            for (int j = 0; j < 4; ++j)
                #pragma unroll
                for (int ks = 0; ks < 2; ++ks)
                    acc[2 + d][j] = __builtin_amdgcn_mfma_f32_16x16x32_bf16(afr[d][ks], bfr[j][ks], acc[2 + d][j], 0, 0, 0);
        __builtin_amdgcn_s_setprio(0);
        fence_barrier();

        // ================= phase 2: A(m4,m5); stage (t+2).B0 ================
        #pragma unroll
        for (int d = 0; d < 2; ++d)
            #pragma unroll
            for (int ks = 0; ks < 2; ++ks)
                afr[d][ks] = *(const bf16x8*)(Asb + (wr + (4 + d) * 16 + l15) * 64 + (((ks * 4 + lq) ^ rx) << 3));
        if (t + 2 < NT) STAGE_B(buf, 0, t + 2);
        fence_barrier();
        asm volatile("s_waitcnt lgkmcnt(0)" ::: "memory");
        __builtin_amdgcn_sched_barrier(0);
        __builtin_amdgcn_s_setprio(1);
        #pragma unroll
        for (int d = 0; d < 2; ++d)
            #pragma unroll
            for (int j = 0; j < 4; ++j)
                #pragma unroll
                for (int ks = 0; ks < 2; ++ks)
                    acc[4 + d][j] = __builtin_amdgcn_mfma_f32_16x16x32_bf16(afr[d][ks], bfr[j][ks], acc[4 + d][j], 0, 0, 0);
        __builtin_amdgcn_s_setprio(0);
        fence_barrier();

        // ================= phase 3: A(m6,m7); stage (t+2).B1; boundary ======
        #pragma unroll
        for (int d = 0; d < 2; ++d)
            #pragma unroll
            for (int ks = 0; ks < 2; ++ks)
                afr[d][ks] = *(const bf16x8*)(Asb + (wr + (6 + d) * 16 + l15) * 64 + (((ks * 4 + lq) ^ rx) << 3));
        if (t + 2 < NT) STAGE_B(buf, 1, t + 2);
        fence_barrier();
        asm volatile("s_waitcnt lgkmcnt(0)" ::: "memory");
        __builtin_amdgcn_sched_barrier(0);
        __builtin_amdgcn_s_setprio(1);
        #pragma unroll
        for (int d = 0; d < 2; ++d)
            #pragma unroll
            for (int j = 0; j < 4; ++j)
                #pragma unroll
                for (int ks = 0; ks < 2; ++ks)
                    acc[6 + d][j] = __builtin_amdgcn_mfma_f32_16x16x32_bf16(afr[d][ks], bfr[j][ks], acc[6 + d][j], 0, 0, 0);
        __builtin_amdgcn_s_setprio(0);
        // tile boundary: guarantee all of tile t+1 (oldest 4 half-tiles) landed.
        if (t < NT - 1) {
            if (t == NT - 2) asm volatile("s_waitcnt vmcnt(0)" ::: "memory");
            else             asm volatile("s_waitcnt vmcnt(4)" ::: "memory");
            fence_barrier();
        }
    }

#undef STAGE_A
#undef STAGE_B

    // epilogue: relu on cols < 1536, bf16 store
    const int crow0 = by * 256 + wr + lq * 4;
    const int ccol0 = bx * 256 + wc + l15;
    #pragma unroll
    for (int mi = 0; mi < 8; ++mi) {
        #pragma unroll
        for (int j = 0; j < 4; ++j) {
            const int gc = ccol0 + j * 16;
            #pragma unroll
            for (int rr = 0; rr < 4; ++rr) {
                const int gr = crow0 + mi * 16 + rr;
                float v = acc[mi][j][rr];
                if (gc < 1536) v = fmaxf(v, 0.0f);
                C[(size_t)gr * N + gc] = __float2bfloat16(v);
            }
        }
    }
}

// C[M,N] = A[M,K] @ B[N,K]^T ; A,B bf16, fp32 accumulate. 128x128 tile.
// (kept for the proj GEMM: 294 blocks at 256^2 would quantize badly)
// MODE 2: += fp32 bias, C fp32.
template<int MODE, typename CT>
__global__ __launch_bounds__(256, 2)
void gemm_bt(const __hip_bfloat16* __restrict__ A,
             const __hip_bfloat16* __restrict__ B,
             CT* __restrict__ C,
             const float* __restrict__ bias,
             int K, int N, int gx)
{
    __shared__ __align__(16) __hip_bfloat16 As[128 * 64];
    __shared__ __align__(16) __hip_bfloat16 Bs[128 * 64];
    const int g = blockIdx.x;
    const int gp = (g & 7) * ((int)gridDim.x >> 3) + (g >> 3);
    const int bx = gp % gx;
    const int by = gp / gx;

    const int tid = threadIdx.x;
    const int w = tid >> 6;
    const int l = tid & 63;
    const int wr = (w >> 1) * 64;
    const int wc = (w & 1) * 64;
    const int l15 = l & 15;
    const int lq = l >> 4;
    const int rx = l15 & 7;

    f32x4 acc[4][4] = {};

    const int srow8 = l >> 3;
    const int scol = (((l & 7) ^ (l >> 3)) << 3);

    const __hip_bfloat16* Ab = A + (size_t)by * 128 * K;
    const __hip_bfloat16* Bb = B + (size_t)bx * 128 * K;

    for (int k0 = 0; k0 < K; k0 += 64) {
        __syncthreads();
        #pragma unroll
        for (int i = 0; i < 4; ++i) {
            const int chunk = w * 4 + i;
            const int row = chunk * 8 + srow8;
            gld_lds16(Ab + (size_t)row * K + (k0 + scol), As + chunk * 512);
            gld_lds16(Bb + (size_t)row * K + (k0 + scol), Bs + chunk * 512);
        }
        __syncthreads();
        #pragma unroll
        for (int kk = 0; kk < 64; kk += 32) {
            const int kb = (kk >> 3) + lq;
            const int col = (kb ^ rx) << 3;
            bf16x8 a[4], b[4];
            #pragma unroll
            for (int i = 0; i < 4; ++i)
                a[i] = *(const bf16x8*)(As + (wr + i * 16 + l15) * 64 + col);
            #pragma unroll
            for (int j = 0; j < 4; ++j)
                b[j] = *(const bf16x8*)(Bs + (wc + j * 16 + l15) * 64 + col);
            #pragma unroll
            for (int i = 0; i < 4; ++i)
                #pragma unroll
                for (int j = 0; j < 4; ++j)
                    acc[i][j] = __builtin_amdgcn_mfma_f32_16x16x32_bf16(a[i], b[j], acc[i][j], 0, 0, 0);
        }
    }

    const int crow0 = by * 128 + wr + lq * 4;
    const int ccol0 = bx * 128 + wc + l15;
    #pragma unroll
    for (int i = 0; i < 4; ++i) {
        #pragma unroll
        for (int j = 0; j < 4; ++j) {
            const int gc = ccol0 + j * 16;
            const float badd = (MODE == 2) ? bias[gc] : 0.0f;
            #pragma unroll
            for (int r = 0; r < 4; ++r) {
                const int gr = crow0 + i * 16 + r;
                float v = acc[i][j][r];
                if (MODE == 1 && gc < 1536) v = fmaxf(v, 0.0f);
                if (MODE == 2) v += badd;
                if (MODE == 1)
                    ((__hip_bfloat16*)C)[(size_t)gr * N + gc] = __float2bfloat16(v);
                else
                    ((float*)C)[(size_t)gr * N + gc] = v;
            }
        }
    }
}

// kv^T[bh][d][e] = sum_s v[s,d]*k[s,e]  (fp32 atomics, split-S x14)
// ksum[bh][e]    = sum_s k[s,e]  via all-ones A-fragment MFMA.
__global__ __launch_bounds__(256)
void kv_mfma_kernel(const __hip_bfloat16* __restrict__ qkv,
                    float* __restrict__ kvg, float* __restrict__ ksumg)
{
    const int SPLIT = 14;
    const int bh = blockIdx.x / SPLIT;
    const int ck = blockIdx.x % SPLIT;
    const int b = bh / 12, h = bh % 12;

    __shared__ __align__(16) __hip_bfloat16 kT[64 * 40];   // [e][s0..31], stride 40
    __shared__ __align__(16) __hip_bfloat16 vT[64 * 40];   // [d][s0..31]

    const int tid = threadIdx.x;
    const int w = tid >> 6, l = tid & 63;
    const int l15 = l & 15, lq = l >> 4;

    const int half = tid >> 7;        // 0 -> stage k, 1 -> stage v
    const int idx  = tid & 127;
    const int e0 = (idx >> 4) * 8;
    const int sp = idx & 15;

    const size_t rowbase = (size_t)b * 3136 * 2304 + (half ? 1536 : 768) + h * 64 + e0;
    __hip_bfloat16* Tdst = half ? vT : kT;

    f32x4 acc[4] = {};
    f32x4 accks = {};

    bf16x8 ones;
    #pragma unroll
    for (int i = 0; i < 8; ++i) ones[i] = (short)0x3F80;   // bf16 1.0

    const int s_begin = ck * 224;
    for (int s0 = s_begin; s0 < s_begin + 224; s0 += 32) {
        __syncthreads();
        bf16x8 r0 = *(const bf16x8*)(qkv + rowbase + (size_t)(s0 + 2 * sp) * 2304);
        bf16x8 r1 = *(const bf16x8*)(qkv + rowbase + (size_t)(s0 + 2 * sp + 1) * 2304);
        #pragma unroll
        for (int qq = 0; qq < 8; ++qq) {
            unsigned pk = ((unsigned)(unsigned short)r0[qq]) |
                          (((unsigned)(unsigned short)r1[qq]) << 16);
            *(unsigned*)(Tdst + (e0 + qq) * 40 + 2 * sp) = pk;
        }
        __syncthreads();
        bf16x8 a = *(const bf16x8*)(vT + (w * 16 + l15) * 40 + lq * 8);
        bf16x8 bfr[4];
        #pragma unroll
        for (int j = 0; j < 4; ++j)
            bfr[j] = *(const bf16x8*)(kT + (j * 16 + l15) * 40 + lq * 8);
        #pragma unroll
        for (int j = 0; j < 4; ++j)
            acc[j] = __builtin_amdgcn_mfma_f32_16x16x32_bf16(a, bfr[j], acc[j], 0, 0, 0);
        accks = __builtin_amdgcn_mfma_f32_16x16x32_bf16(ones, bfr[w], accks, 0, 0, 0);
    }

    float* kvdst = kvg + ((size_t)bh << 12);
    #pragma unroll
    for (int j = 0; j < 4; ++j) {
        const int col = j * 16 + l15;
        #pragma unroll
        for (int r = 0; r < 4; ++r) {
            const int row = w * 16 + lq * 4 + r;
            atomicAdd(kvdst + row * 64 + col, acc[j][r]);
        }
    }
    if (lq == 0)
        atomicAdd(ksumg + (bh << 6) + w * 16 + l15, accks[0]);
}

// att[m, h*64+d] = (q[m,:] @ kv^T[d,:]) * 1/(q[m,:].ksum + eps)
__global__ __launch_bounds__(256)
void attn_mfma2(const __hip_bfloat16* __restrict__ qkv,
                const __hip_bfloat16* __restrict__ kvb,
                const float* __restrict__ ksumg,
                __hip_bfloat16* __restrict__ att)
{
    const int bh = blockIdx.x / 49;
    const int mt = blockIdx.x % 49;
    const int b = bh / 12, h = bh % 12;
    const int tid = threadIdx.x;
    const int w = tid >> 6, l = tid & 63;
    const int l15 = l & 15, lq = l >> 4;

    const size_t m0 = (size_t)b * 3136 + (size_t)mt * 64 + w * 16;

    const __hip_bfloat16* qrow = qkv + (m0 + l15) * 2304 + h * 64;
    bf16x8 aq0 = *(const bf16x8*)(qrow + lq * 8);
    bf16x8 aq1 = *(const bf16x8*)(qrow + 32 + lq * 8);

    const float* ks = ksumg + (bh << 6);
    float kse[8], kse1[8];
    *(float4*)(kse)      = *(const float4*)(ks + lq * 8);
    *(float4*)(kse + 4)  = *(const float4*)(ks + lq * 8 + 4);
    *(float4*)(kse1)     = *(const float4*)(ks + 32 + lq * 8);
    *(float4*)(kse1 + 4) = *(const float4*)(ks + 32 + lq * 8 + 4);
    float zp = 0.0f;
    #pragma unroll
    for (int j = 0; j < 8; ++j)
        zp += b2f(aq0[j]) * kse[j] + b2f(aq1[j]) * kse1[j];
    zp += __shfl_xor(zp, 16);
    zp += __shfl_xor(zp, 32);
    const float zr = 1.0f / (zp + EPS_Z);   // lane i<16 holds z-recip for row i

    const __hip_bfloat16* kvh = kvb + ((size_t)bh << 12);
    f32x4 acc[4] = {};
    #pragma unroll
    for (int j = 0; j < 4; ++j) {
        bf16x8 b0 = *(const bf16x8*)(kvh + (j * 16 + l15) * 64 + lq * 8);
        bf16x8 b1 = *(const bf16x8*)(kvh + (j * 16 + l15) * 64 + 32 + lq * 8);
        acc[j] = __builtin_amdgcn_mfma_f32_16x16x32_bf16(aq0, b0, acc[j], 0, 0, 0);
        acc[j] = __builtin_amdgcn_mfma_f32_16x16x32_bf16(aq1, b1, acc[j], 0, 0, 0);
    }

    float zrow[4];
    #pragma unroll
    for (int r = 0; r < 4; ++r) zrow[r] = __shfl(zr, lq * 4 + r);

    #pragma unroll
    for (int j = 0; j < 4; ++j) {
        const int col = j * 16 + l15;
        #pragma unroll
        for (int r = 0; r < 4; ++r) {
            const int row = lq * 4 + r;
            att[(m0 + row) * 768 + h * 64 + col] = __float2bfloat16(acc[j][r] * zrow[r]);
        }
    }
}

extern "C" void kernel_launch(void* const* d_in, const int* in_sizes, int n_in,
                              void* d_out, int out_size, void* d_ws, size_t ws_size,
                              hipStream_t stream)
{
    const float* x      = (const float*)d_in[0];   // [25088, 768]
    const float* W_qkv  = (const float*)d_in[1];   // [2304, 768]
    const float* W_proj = (const float*)d_in[2];   // [768, 768]
    const float* b_proj = (const float*)d_in[3];   // [768]
    float* out = (float*)d_out;

    const int M = 25088, K = 768, N1 = 2304, N2 = 768;

    __hip_bfloat16* qkv = (__hip_bfloat16*)d_ws;            // M*N1
    __hip_bfloat16* xb  = qkv + (size_t)M * N1;             // M*K
    __hip_bfloat16* wqb = xb + (size_t)M * K;               // N1*K
    __hip_bfloat16* wpb = wqb + (size_t)N1 * K;             // N2*K
    float* kvg  = (float*)(wpb + (size_t)N2 * K);           // 96*4096 fp32 (kv^T [bh][d][e])
    float* ksum = kvg + 96 * 4096;                          // 96*64 fp32
    __hip_bfloat16* kvb = (__hip_bfloat16*)(ksum + 96 * 64);// 96*4096 bf16
    __hip_bfloat16* att = xb;                               // alias: M*N2 <= M*K

    hipMemsetAsync(kvg, 0, (size_t)(96 * 4096 + 96 * 64) * sizeof(float), stream);

    cvt_f32_bf16<<<(M * K / 4 + 255) / 256, 256, 0, stream>>>(x, xb, M * K / 4);
    cvt_f32_bf16<<<(N1 * K / 4 + 255) / 256, 256, 0, stream>>>(W_qkv, wqb, N1 * K / 4);
    cvt_f32_bf16<<<(N2 * K / 4 + 255) / 256, 256, 0, stream>>>(W_proj, wpb, N2 * K / 4);

    gemm256_relu<<<(M / 256) * (N1 / 256), 512, 0, stream>>>(
        xb, wqb, qkv, K, N1, N1 / 256);
    kv_mfma_kernel<<<96 * 14, 256, 0, stream>>>(qkv, kvg, ksum);
    cvt_f32_bf16<<<(96 * 4096 / 4 + 255) / 256, 256, 0, stream>>>(kvg, kvb, 96 * 4096 / 4);
    attn_mfma2<<<96 * 49, 256, 0, stream>>>(qkv, kvb, ksum, att);
    gemm_bt<2, float><<<(M / 128) * (N2 / 128), 256, 0, stream>>>(
        att, wpb, out, b_proj, K, N2, N2 / 128);
}

// Round 2
// 349.910 us; speedup vs baseline: 1.0590x; 1.0590x over previous
//
#include <hip/hip_runtime.h>
#include <hip/hip_bf16.h>

#define EPS_Z 1e-4f

typedef __attribute__((ext_vector_type(8))) short bf16x8;
typedef __attribute__((ext_vector_type(4))) float f32x4;

__device__ __forceinline__ float b2f(short s) {
    union { unsigned u; float f; } cv;
    cv.u = ((unsigned)(unsigned short)s) << 16;
    return cv.f;
}

__device__ __forceinline__ void gld_lds16(const __hip_bfloat16* g, __hip_bfloat16* l) {
    __builtin_amdgcn_global_load_lds(
        (__attribute__((address_space(1))) void*)(g),
        (__attribute__((address_space(3))) void*)(l),
        16, 0, 0);
}

// fp32 -> bf16 (RNE), 4 elems/thread
__global__ __launch_bounds__(256)
void cvt_f32_bf16(const float* __restrict__ in, __hip_bfloat16* __restrict__ out, int n4)
{
    int i = blockIdx.x * 256 + threadIdx.x;
    if (i >= n4) return;
    float4 v = ((const float4*)in)[i];
    union { short4 s; __hip_bfloat16 h[4]; } o;
    o.h[0] = __float2bfloat16(v.x);
    o.h[1] = __float2bfloat16(v.y);
    o.h[2] = __float2bfloat16(v.z);
    o.h[3] = __float2bfloat16(v.w);
    ((short4*)out)[i] = o.s;
}

// C[M,N] = A[M,K] @ B[N,K]^T ; A,B bf16, fp32 accumulate. 128x128 tile, 2 blocks/CU.
// PROVEN 929 TF on this shape (round 0). Do not touch.
// MODE 1: relu on cols < 1536, C bf16. MODE 2: += fp32 bias, C fp32.
template<int MODE, typename CT>
__global__ __launch_bounds__(256, 2)
void gemm_bt(const __hip_bfloat16* __restrict__ A,
             const __hip_bfloat16* __restrict__ B,
             CT* __restrict__ C,
             const float* __restrict__ bias,
             int K, int N, int gx)
{
    __shared__ __align__(16) __hip_bfloat16 As[128 * 64];
    __shared__ __align__(16) __hip_bfloat16 Bs[128 * 64];
    const int g = blockIdx.x;
    const int gp = (g & 7) * ((int)gridDim.x >> 3) + (g >> 3);
    const int bx = gp % gx;
    const int by = gp / gx;

    const int tid = threadIdx.x;
    const int w = tid >> 6;
    const int l = tid & 63;
    const int wr = (w >> 1) * 64;
    const int wc = (w & 1) * 64;
    const int l15 = l & 15;
    const int lq = l >> 4;
    const int rx = l15 & 7;

    f32x4 acc[4][4] = {};

    const int srow8 = l >> 3;
    const int scol = (((l & 7) ^ (l >> 3)) << 3);

    const __hip_bfloat16* Ab = A + (size_t)by * 128 * K;
    const __hip_bfloat16* Bb = B + (size_t)bx * 128 * K;

    for (int k0 = 0; k0 < K; k0 += 64) {
        __syncthreads();
        #pragma unroll
        for (int i = 0; i < 4; ++i) {
            const int chunk = w * 4 + i;
            const int row = chunk * 8 + srow8;
            gld_lds16(Ab + (size_t)row * K + (k0 + scol), As + chunk * 512);
            gld_lds16(Bb + (size_t)row * K + (k0 + scol), Bs + chunk * 512);
        }
        __syncthreads();
        #pragma unroll
        for (int kk = 0; kk < 64; kk += 32) {
            const int kb = (kk >> 3) + lq;
            const int col = (kb ^ rx) << 3;
            bf16x8 a[4], b[4];
            #pragma unroll
            for (int i = 0; i < 4; ++i)
                a[i] = *(const bf16x8*)(As + (wr + i * 16 + l15) * 64 + col);
            #pragma unroll
            for (int j = 0; j < 4; ++j)
                b[j] = *(const bf16x8*)(Bs + (wc + j * 16 + l15) * 64 + col);
            #pragma unroll
            for (int i = 0; i < 4; ++i)
                #pragma unroll
                for (int j = 0; j < 4; ++j)
                    acc[i][j] = __builtin_amdgcn_mfma_f32_16x16x32_bf16(a[i], b[j], acc[i][j], 0, 0, 0);
        }
    }

    const int crow0 = by * 128 + wr + lq * 4;
    const int ccol0 = bx * 128 + wc + l15;
    #pragma unroll
    for (int i = 0; i < 4; ++i) {
        #pragma unroll
        for (int j = 0; j < 4; ++j) {
            const int gc = ccol0 + j * 16;
            const float badd = (MODE == 2) ? bias[gc] : 0.0f;
            #pragma unroll
            for (int r = 0; r < 4; ++r) {
                const int gr = crow0 + i * 16 + r;
                float v = acc[i][j][r];
                if (MODE == 1 && gc < 1536) v = fmaxf(v, 0.0f);
                if (MODE == 2) v += badd;
                if (MODE == 1)
                    ((__hip_bfloat16*)C)[(size_t)gr * N + gc] = __float2bfloat16(v);
                else
                    ((float*)C)[(size_t)gr * N + gc] = v;
            }
        }
    }
}

// kv^T partials: kvp[(bh*7+ck)][d][e] = sum_{s in split ck} v[s,d]*k[s,e]
// ksump[(bh*7+ck)][e] = sum_{s in split ck} k[s,e]  (all-ones A-fragment MFMA)
// Plain coalesced fp32 stores -- NO global atomics (was 5.5M atomicAdds).
__global__ __launch_bounds__(256)
void kv_mfma_kernel(const __hip_bfloat16* __restrict__ qkv,
                    float* __restrict__ kvp, float* __restrict__ ksump)
{
    const int SPLIT = 7;
    const int bh = blockIdx.x / SPLIT;
    const int ck = blockIdx.x % SPLIT;
    const int b = bh / 12, h = bh % 12;

    __shared__ __align__(16) __hip_bfloat16 kT[64 * 40];   // [e][s0..31], stride 40
    __shared__ __align__(16) __hip_bfloat16 vT[64 * 40];   // [d][s0..31]

    const int tid = threadIdx.x;
    const int w = tid >> 6, l = tid & 63;
    const int l15 = l & 15, lq = l >> 4;

    const int half = tid >> 7;        // 0 -> stage k, 1 -> stage v
    const int idx  = tid & 127;
    const int e0 = (idx >> 4) * 8;
    const int sp = idx & 15;

    const size_t rowbase = (size_t)b * 3136 * 2304 + (half ? 1536 : 768) + h * 64 + e0;
    __hip_bfloat16* Tdst = half ? vT : kT;

    f32x4 acc[4] = {};
    f32x4 accks = {};

    bf16x8 ones;
    #pragma unroll
    for (int i = 0; i < 8; ++i) ones[i] = (short)0x3F80;   // bf16 1.0

    const int s_begin = ck * 448;
    for (int s0 = s_begin; s0 < s_begin + 448; s0 += 32) {
        __syncthreads();
        bf16x8 r0 = *(const bf16x8*)(qkv + rowbase + (size_t)(s0 + 2 * sp) * 2304);
        bf16x8 r1 = *(const bf16x8*)(qkv + rowbase + (size_t)(s0 + 2 * sp + 1) * 2304);
        #pragma unroll
        for (int qq = 0; qq < 8; ++qq) {
            unsigned pk = ((unsigned)(unsigned short)r0[qq]) |
                          (((unsigned)(unsigned short)r1[qq]) << 16);
            *(unsigned*)(Tdst + (e0 + qq) * 40 + 2 * sp) = pk;
        }
        __syncthreads();
        bf16x8 a = *(const bf16x8*)(vT + (w * 16 + l15) * 40 + lq * 8);
        bf16x8 bfr[4];
        #pragma unroll
        for (int j = 0; j < 4; ++j)
            bfr[j] = *(const bf16x8*)(kT + (j * 16 + l15) * 40 + lq * 8);
        #pragma unroll
        for (int j = 0; j < 4; ++j)
            acc[j] = __builtin_amdgcn_mfma_f32_16x16x32_bf16(a, bfr[j], acc[j], 0, 0, 0);
        accks = __builtin_amdgcn_mfma_f32_16x16x32_bf16(ones, bfr[w], accks, 0, 0, 0);
    }

    float* kvdst = kvp + ((size_t)(bh * SPLIT + ck) << 12);
    #pragma unroll
    for (int j = 0; j < 4; ++j) {
        const int col = j * 16 + l15;
        #pragma unroll
        for (int r = 0; r < 4; ++r) {
            const int row = w * 16 + lq * 4 + r;
            kvdst[row * 64 + col] = acc[j][r];
        }
    }
    if (lq == 0)
        ksump[(size_t)(bh * SPLIT + ck) * 64 + w * 16 + l15] = accks[0];
}

// Sum the 7 fp32 partials -> kvb (bf16) and ksum (fp32). Replaces the old
// kvg memset + atomic target + separate cvt dispatch.
__global__ __launch_bounds__(256)
void kv_reduce(const float* __restrict__ kvp, const float* __restrict__ ksump,
               __hip_bfloat16* __restrict__ kvb, float* __restrict__ ksum)
{
    const int SPLIT = 7;
    const int bh = blockIdx.x;
    const int tid = threadIdx.x;

    const float* base = kvp + ((size_t)bh * SPLIT << 12) + tid * 16;
    float4 s0 = {}, s1 = {}, s2 = {}, s3 = {};
    #pragma unroll
    for (int p = 0; p < SPLIT; ++p) {
        const float* bp = base + ((size_t)p << 12);
        float4 a0 = *(const float4*)(bp + 0);
        float4 a1 = *(const float4*)(bp + 4);
        float4 a2 = *(const float4*)(bp + 8);
        float4 a3 = *(const float4*)(bp + 12);
        s0.x += a0.x; s0.y += a0.y; s0.z += a0.z; s0.w += a0.w;
        s1.x += a1.x; s1.y += a1.y; s1.z += a1.z; s1.w += a1.w;
        s2.x += a2.x; s2.y += a2.y; s2.z += a2.z; s2.w += a2.w;
        s3.x += a3.x; s3.y += a3.y; s3.z += a3.z; s3.w += a3.w;
    }
    union { bf16x8 v; __hip_bfloat16 h[8]; } o0, o1;
    o0.h[0] = __float2bfloat16(s0.x); o0.h[1] = __float2bfloat16(s0.y);
    o0.h[2] = __float2bfloat16(s0.z); o0.h[3] = __float2bfloat16(s0.w);
    o0.h[4] = __float2bfloat16(s1.x); o0.h[5] = __float2bfloat16(s1.y);
    o0.h[6] = __float2bfloat16(s1.z); o0.h[7] = __float2bfloat16(s1.w);
    o1.h[0] = __float2bfloat16(s2.x); o1.h[1] = __float2bfloat16(s2.y);
    o1.h[2] = __float2bfloat16(s2.z); o1.h[3] = __float2bfloat16(s2.w);
    o1.h[4] = __float2bfloat16(s3.x); o1.h[5] = __float2bfloat16(s3.y);
    o1.h[6] = __float2bfloat16(s3.z); o1.h[7] = __float2bfloat16(s3.w);
    __hip_bfloat16* dst = kvb + ((size_t)bh << 12) + tid * 16;
    *(bf16x8*)(dst + 0) = o0.v;
    *(bf16x8*)(dst + 8) = o1.v;

    if (tid < 64) {
        float t = 0.0f;
        #pragma unroll
        for (int p = 0; p < SPLIT; ++p)
            t += ksump[(size_t)(bh * SPLIT + p) * 64 + tid];
        ksum[(size_t)bh * 64 + tid] = t;
    }
}

// att[m, h*64+d] = (q[m,:] @ kv^T[d,:]) * 1/(q[m,:].ksum + eps)
__global__ __launch_bounds__(256)
void attn_mfma2(const __hip_bfloat16* __restrict__ qkv,
                const __hip_bfloat16* __restrict__ kvb,
                const float* __restrict__ ksumg,
                __hip_bfloat16* __restrict__ att)
{
    const int bh = blockIdx.x / 49;
    const int mt = blockIdx.x % 49;
    const int b = bh / 12, h = bh % 12;
    const int tid = threadIdx.x;
    const int w = tid >> 6, l = tid & 63;
    const int l15 = l & 15, lq = l >> 4;

    const size_t m0 = (size_t)b * 3136 + (size_t)mt * 64 + w * 16;

    const __hip_bfloat16* qrow = qkv + (m0 + l15) * 2304 + h * 64;
    bf16x8 aq0 = *(const bf16x8*)(qrow + lq * 8);
    bf16x8 aq1 = *(const bf16x8*)(qrow + 32 + lq * 8);

    const float* ks = ksumg + (bh << 6);
    float kse[8], kse1[8];
    *(float4*)(kse)      = *(const float4*)(ks + lq * 8);
    *(float4*)(kse + 4)  = *(const float4*)(ks + lq * 8 + 4);
    *(float4*)(kse1)     = *(const float4*)(ks + 32 + lq * 8);
    *(float4*)(kse1 + 4) = *(const float4*)(ks + 32 + lq * 8 + 4);
    float zp = 0.0f;
    #pragma unroll
    for (int j = 0; j < 8; ++j)
        zp += b2f(aq0[j]) * kse[j] + b2f(aq1[j]) * kse1[j];
    zp += __shfl_xor(zp, 16);
    zp += __shfl_xor(zp, 32);
    const float zr = 1.0f / (zp + EPS_Z);   // lane i<16 holds z-recip for row i

    const __hip_bfloat16* kvh = kvb + ((size_t)bh << 12);
    f32x4 acc[4] = {};
    #pragma unroll
    for (int j = 0; j < 4; ++j) {
        bf16x8 b0 = *(const bf16x8*)(kvh + (j * 16 + l15) * 64 + lq * 8);
        bf16x8 b1 = *(const bf16x8*)(kvh + (j * 16 + l15) * 64 + 32 + lq * 8);
        acc[j] = __builtin_amdgcn_mfma_f32_16x16x32_bf16(aq0, b0, acc[j], 0, 0, 0);
        acc[j] = __builtin_amdgcn_mfma_f32_16x16x32_bf16(aq1, b1, acc[j], 0, 0, 0);
    }

    float zrow[4];
    #pragma unroll
    for (int r = 0; r < 4; ++r) zrow[r] = __shfl(zr, lq * 4 + r);

    #pragma unroll
    for (int j = 0; j < 4; ++j) {
        const int col = j * 16 + l15;
        #pragma unroll
        for (int r = 0; r < 4; ++r) {
            const int row = lq * 4 + r;
            att[(m0 + row) * 768 + h * 64 + col] = __float2bfloat16(acc[j][r] * zrow[r]);
        }
    }
}

extern "C" void kernel_launch(void* const* d_in, const int* in_sizes, int n_in,
                              void* d_out, int out_size, void* d_ws, size_t ws_size,
                              hipStream_t stream)
{
    const float* x      = (const float*)d_in[0];   // [25088, 768]
    const float* W_qkv  = (const float*)d_in[1];   // [2304, 768]
    const float* W_proj = (const float*)d_in[2];   // [768, 768]
    const float* b_proj = (const float*)d_in[3];   // [768]
    float* out = (float*)d_out;

    const int M = 25088, K = 768, N1 = 2304, N2 = 768;
    const int SPLIT = 7;

    __hip_bfloat16* qkv = (__hip_bfloat16*)d_ws;            // M*N1
    __hip_bfloat16* xb  = qkv + (size_t)M * N1;             // M*K
    __hip_bfloat16* wqb = xb + (size_t)M * K;               // N1*K
    __hip_bfloat16* wpb = wqb + (size_t)N1 * K;             // N2*K
    float* kvp   = (float*)(wpb + (size_t)N2 * K);          // 7*96*4096 fp32 partials
    float* ksump = kvp + (size_t)SPLIT * 96 * 4096;         // 7*96*64 fp32 partials
    float* ksum  = ksump + (size_t)SPLIT * 96 * 64;         // 96*64 fp32
    __hip_bfloat16* kvb = (__hip_bfloat16*)(ksum + 96 * 64);// 96*4096 bf16
    __hip_bfloat16* att = xb;                               // alias: M*N2 <= M*K

    cvt_f32_bf16<<<(M * K / 4 + 255) / 256, 256, 0, stream>>>(x, xb, M * K / 4);
    cvt_f32_bf16<<<(N1 * K / 4 + 255) / 256, 256, 0, stream>>>(W_qkv, wqb, N1 * K / 4);
    cvt_f32_bf16<<<(N2 * K / 4 + 255) / 256, 256, 0, stream>>>(W_proj, wpb, N2 * K / 4);

    gemm_bt<1, __hip_bfloat16><<<(M / 128) * (N1 / 128), 256, 0, stream>>>(
        xb, wqb, qkv, nullptr, K, N1, N1 / 128);
    kv_mfma_kernel<<<96 * SPLIT, 256, 0, stream>>>(qkv, kvp, ksump);
    kv_reduce<<<96, 256, 0, stream>>>(kvp, ksump, kvb, ksum);
    attn_mfma2<<<96 * 49, 256, 0, stream>>>(qkv, kvb, ksum, att);
    gemm_bt<2, float><<<(M / 128) * (N2 / 128), 256, 0, stream>>>(
        att, wpb, out, b_proj, K, N2, N2 / 128);
}

// Round 3
// 336.198 us; speedup vs baseline: 1.1022x; 1.0408x over previous
//
#include <hip/hip_runtime.h>
#include <hip/hip_bf16.h>

#define EPS_Z 1e-4f

typedef __attribute__((ext_vector_type(8))) short bf16x8;
typedef __attribute__((ext_vector_type(4))) float f32x4;

__device__ __forceinline__ float b2f(short s) {
    union { unsigned u; float f; } cv;
    cv.u = ((unsigned)(unsigned short)s) << 16;
    return cv.f;
}

__device__ __forceinline__ void gld_lds16(const __hip_bfloat16* g, __hip_bfloat16* l) {
    __builtin_amdgcn_global_load_lds(
        (__attribute__((address_space(1))) void*)(g),
        (__attribute__((address_space(3))) void*)(l),
        16, 0, 0);
}

// One dispatch converting x, W_qkv, W_proj (fp32 -> bf16 RNE, 4 elems/thread).
__global__ __launch_bounds__(256)
void cvt_all(const float* __restrict__ x, const float* __restrict__ wq,
             const float* __restrict__ wp,
             __hip_bfloat16* __restrict__ xb, __hip_bfloat16* __restrict__ wqb,
             __hip_bfloat16* __restrict__ wpb)
{
    const int N4X = 25088 * 768 / 4;          // 4,816,896
    const int N4Q = 2304 * 768 / 4;           //   442,368
    const int N4P = 768 * 768 / 4;            //   147,456
    int i = blockIdx.x * 256 + threadIdx.x;
    const float* src;
    __hip_bfloat16* dst;
    int idx;
    if (i < N4X)            { src = x;  dst = xb;  idx = i; }
    else if (i < N4X + N4Q) { src = wq; dst = wqb; idx = i - N4X; }
    else if (i < N4X + N4Q + N4P) { src = wp; dst = wpb; idx = i - N4X - N4Q; }
    else return;
    float4 v = ((const float4*)src)[idx];
    union { short4 s; __hip_bfloat16 h[4]; } o;
    o.h[0] = __float2bfloat16(v.x);
    o.h[1] = __float2bfloat16(v.y);
    o.h[2] = __float2bfloat16(v.z);
    o.h[3] = __float2bfloat16(v.w);
    ((short4*)dst)[idx] = o.s;
}

// C[M,N] = A[M,K] @ B[N,K]^T ; A,B bf16, fp32 accumulate. 128x128 tile.
// (256,3): one more resident block per CU to hide the per-K-step barrier drain
// (m114 mechanism). VGPR=64 well under the 170/wave budget at 3 blocks/CU.
// MODE 1: relu on cols < 1536, C bf16. MODE 2: += fp32 bias, C fp32.
template<int MODE, typename CT>
__global__ __launch_bounds__(256, 3)
void gemm_bt(const __hip_bfloat16* __restrict__ A,
             const __hip_bfloat16* __restrict__ B,
             CT* __restrict__ C,
             const float* __restrict__ bias,
             int K, int N, int gx)
{
    __shared__ __align__(16) __hip_bfloat16 As[128 * 64];
    __shared__ __align__(16) __hip_bfloat16 Bs[128 * 64];
    const int g = blockIdx.x;
    const int gp = (g & 7) * ((int)gridDim.x >> 3) + (g >> 3);
    const int bx = gp % gx;
    const int by = gp / gx;

    const int tid = threadIdx.x;
    const int w = tid >> 6;
    const int l = tid & 63;
    const int wr = (w >> 1) * 64;
    const int wc = (w & 1) * 64;
    const int l15 = l & 15;
    const int lq = l >> 4;
    const int rx = l15 & 7;

    f32x4 acc[4][4] = {};

    const int srow8 = l >> 3;
    const int scol = (((l & 7) ^ (l >> 3)) << 3);

    const __hip_bfloat16* Ab = A + (size_t)by * 128 * K;
    const __hip_bfloat16* Bb = B + (size_t)bx * 128 * K;

    for (int k0 = 0; k0 < K; k0 += 64) {
        __syncthreads();
        #pragma unroll
        for (int i = 0; i < 4; ++i) {
            const int chunk = w * 4 + i;
            const int row = chunk * 8 + srow8;
            gld_lds16(Ab + (size_t)row * K + (k0 + scol), As + chunk * 512);
            gld_lds16(Bb + (size_t)row * K + (k0 + scol), Bs + chunk * 512);
        }
        __syncthreads();
        #pragma unroll
        for (int kk = 0; kk < 64; kk += 32) {
            const int kb = (kk >> 3) + lq;
            const int col = (kb ^ rx) << 3;
            bf16x8 a[4], b[4];
            #pragma unroll
            for (int i = 0; i < 4; ++i)
                a[i] = *(const bf16x8*)(As + (wr + i * 16 + l15) * 64 + col);
            #pragma unroll
            for (int j = 0; j < 4; ++j)
                b[j] = *(const bf16x8*)(Bs + (wc + j * 16 + l15) * 64 + col);
            #pragma unroll
            for (int i = 0; i < 4; ++i)
                #pragma unroll
                for (int j = 0; j < 4; ++j)
                    acc[i][j] = __builtin_amdgcn_mfma_f32_16x16x32_bf16(a[i], b[j], acc[i][j], 0, 0, 0);
        }
    }

    const int crow0 = by * 128 + wr + lq * 4;
    const int ccol0 = bx * 128 + wc + l15;
    #pragma unroll
    for (int i = 0; i < 4; ++i) {
        #pragma unroll
        for (int j = 0; j < 4; ++j) {
            const int gc = ccol0 + j * 16;
            const float badd = (MODE == 2) ? bias[gc] : 0.0f;
            #pragma unroll
            for (int r = 0; r < 4; ++r) {
                const int gr = crow0 + i * 16 + r;
                float v = acc[i][j][r];
                if (MODE == 1 && gc < 1536) v = fmaxf(v, 0.0f);
                if (MODE == 2) v += badd;
                if (MODE == 1)
                    ((__hip_bfloat16*)C)[(size_t)gr * N + gc] = __float2bfloat16(v);
                else
                    ((float*)C)[(size_t)gr * N + gc] = v;
            }
        }
    }
}

// kv^T partials: kvp[(bh*7+ck)][d][e] = sum_{s in split ck} v[s,d]*k[s,e]
// ksump[(bh*7+ck)][e] = sum_{s in split ck} k[s,e]  (all-ones A-fragment MFMA)
// Software-pipelined: next s-block's global loads issue before this block's MFMA,
// hiding HBM latency under ds_read+MFMA instead of exposing it between barriers.
__global__ __launch_bounds__(256)
void kv_mfma_kernel(const __hip_bfloat16* __restrict__ qkv,
                    float* __restrict__ kvp, float* __restrict__ ksump)
{
    const int SPLIT = 7;
    const int bh = blockIdx.x / SPLIT;
    const int ck = blockIdx.x % SPLIT;
    const int b = bh / 12, h = bh % 12;

    __shared__ __align__(16) __hip_bfloat16 kT[64 * 40];   // [e][s0..31], stride 40
    __shared__ __align__(16) __hip_bfloat16 vT[64 * 40];   // [d][s0..31]

    const int tid = threadIdx.x;
    const int w = tid >> 6, l = tid & 63;
    const int l15 = l & 15, lq = l >> 4;

    const int half = tid >> 7;        // 0 -> stage k, 1 -> stage v
    const int idx  = tid & 127;
    const int e0 = (idx >> 4) * 8;
    const int sp = idx & 15;

    const size_t rowbase = (size_t)b * 3136 * 2304 + (half ? 1536 : 768) + h * 64 + e0;
    __hip_bfloat16* Tdst = half ? vT : kT;

    f32x4 acc[4] = {};
    f32x4 accks = {};

    bf16x8 ones;
    #pragma unroll
    for (int i = 0; i < 8; ++i) ones[i] = (short)0x3F80;   // bf16 1.0

    const int s_begin = ck * 448;
    const int s_end = s_begin + 448;

    bf16x8 r0 = *(const bf16x8*)(qkv + rowbase + (size_t)(s_begin + 2 * sp) * 2304);
    bf16x8 r1 = *(const bf16x8*)(qkv + rowbase + (size_t)(s_begin + 2 * sp + 1) * 2304);

    for (int s0 = s_begin; s0 < s_end; s0 += 32) {
        __syncthreads();   // previous compute done reading LDS
        #pragma unroll
        for (int qq = 0; qq < 8; ++qq) {
            unsigned pk = ((unsigned)(unsigned short)r0[qq]) |
                          (((unsigned)(unsigned short)r1[qq]) << 16);
            *(unsigned*)(Tdst + (e0 + qq) * 40 + 2 * sp) = pk;
        }
        __syncthreads();   // staged data visible
        if (s0 + 32 < s_end) {   // prefetch next block; hides under MFMA below
            r0 = *(const bf16x8*)(qkv + rowbase + (size_t)(s0 + 32 + 2 * sp) * 2304);
            r1 = *(const bf16x8*)(qkv + rowbase + (size_t)(s0 + 33 + 2 * sp) * 2304);
        }
        bf16x8 a = *(const bf16x8*)(vT + (w * 16 + l15) * 40 + lq * 8);
        bf16x8 bfr[4];
        #pragma unroll
        for (int j = 0; j < 4; ++j)
            bfr[j] = *(const bf16x8*)(kT + (j * 16 + l15) * 40 + lq * 8);
        #pragma unroll
        for (int j = 0; j < 4; ++j)
            acc[j] = __builtin_amdgcn_mfma_f32_16x16x32_bf16(a, bfr[j], acc[j], 0, 0, 0);
        accks = __builtin_amdgcn_mfma_f32_16x16x32_bf16(ones, bfr[w], accks, 0, 0, 0);
    }

    float* kvdst = kvp + ((size_t)(bh * SPLIT + ck) << 12);
    #pragma unroll
    for (int j = 0; j < 4; ++j) {
        const int col = j * 16 + l15;
        #pragma unroll
        for (int r = 0; r < 4; ++r) {
            const int row = w * 16 + lq * 4 + r;
            kvdst[row * 64 + col] = acc[j][r];
        }
    }
    if (lq == 0)
        ksump[(size_t)(bh * SPLIT + ck) * 64 + w * 16 + l15] = accks[0];
}

// Sum the 7 fp32 partials -> kvb (bf16) and ksum (fp32).
__global__ __launch_bounds__(256)
void kv_reduce(const float* __restrict__ kvp, const float* __restrict__ ksump,
               __hip_bfloat16* __restrict__ kvb, float* __restrict__ ksum)
{
    const int SPLIT = 7;
    const int bh = blockIdx.x;
    const int tid = threadIdx.x;

    const float* base = kvp + ((size_t)bh * SPLIT << 12) + tid * 16;
    float4 s0 = {}, s1 = {}, s2 = {}, s3 = {};
    #pragma unroll
    for (int p = 0; p < SPLIT; ++p) {
        const float* bp = base + ((size_t)p << 12);
        float4 a0 = *(const float4*)(bp + 0);
        float4 a1 = *(const float4*)(bp + 4);
        float4 a2 = *(const float4*)(bp + 8);
        float4 a3 = *(const float4*)(bp + 12);
        s0.x += a0.x; s0.y += a0.y; s0.z += a0.z; s0.w += a0.w;
        s1.x += a1.x; s1.y += a1.y; s1.z += a1.z; s1.w += a1.w;
        s2.x += a2.x; s2.y += a2.y; s2.z += a2.z; s2.w += a2.w;
        s3.x += a3.x; s3.y += a3.y; s3.z += a3.z; s3.w += a3.w;
    }
    union { bf16x8 v; __hip_bfloat16 h[8]; } o0, o1;
    o0.h[0] = __float2bfloat16(s0.x); o0.h[1] = __float2bfloat16(s0.y);
    o0.h[2] = __float2bfloat16(s0.z); o0.h[3] = __float2bfloat16(s0.w);
    o0.h[4] = __float2bfloat16(s1.x); o0.h[5] = __float2bfloat16(s1.y);
    o0.h[6] = __float2bfloat16(s1.z); o0.h[7] = __float2bfloat16(s1.w);
    o1.h[0] = __float2bfloat16(s2.x); o1.h[1] = __float2bfloat16(s2.y);
    o1.h[2] = __float2bfloat16(s2.z); o1.h[3] = __float2bfloat16(s2.w);
    o1.h[4] = __float2bfloat16(s3.x); o1.h[5] = __float2bfloat16(s3.y);
    o1.h[6] = __float2bfloat16(s3.z); o1.h[7] = __float2bfloat16(s3.w);
    __hip_bfloat16* dst = kvb + ((size_t)bh << 12) + tid * 16;
    *(bf16x8*)(dst + 0) = o0.v;
    *(bf16x8*)(dst + 8) = o1.v;

    if (tid < 64) {
        float t = 0.0f;
        #pragma unroll
        for (int p = 0; p < SPLIT; ++p)
            t += ksump[(size_t)(bh * SPLIT + p) * 64 + tid];
        ksum[(size_t)bh * 64 + tid] = t;
    }
}

// att[m, h*64+d] = (q[m,:] @ kv^T[d,:]) * 1/(q[m,:].ksum + eps)
// 2 row-tiles (2x64 rows) per block: kvb B-fragments + ksum loaded once, reused.
__global__ __launch_bounds__(256)
void attn_mfma2(const __hip_bfloat16* __restrict__ qkv,
                const __hip_bfloat16* __restrict__ kvb,
                const float* __restrict__ ksumg,
                __hip_bfloat16* __restrict__ att)
{
    const int bh = blockIdx.x / 25;
    const int u  = blockIdx.x % 25;
    const int b = bh / 12, h = bh % 12;
    const int tid = threadIdx.x;
    const int w = tid >> 6, l = tid & 63;
    const int l15 = l & 15, lq = l >> 4;

    // B-fragments from kvb[bh][d][e] (row-major, stride 64) -- loaded once
    const __hip_bfloat16* kvh = kvb + ((size_t)bh << 12);
    bf16x8 b0[4], b1[4];
    #pragma unroll
    for (int j = 0; j < 4; ++j) {
        b0[j] = *(const bf16x8*)(kvh + (j * 16 + l15) * 64 + lq * 8);
        b1[j] = *(const bf16x8*)(kvh + (j * 16 + l15) * 64 + 32 + lq * 8);
    }
    const float* ks = ksumg + (bh << 6);
    float kse[8], kse1[8];
    *(float4*)(kse)      = *(const float4*)(ks + lq * 8);
    *(float4*)(kse + 4)  = *(const float4*)(ks + lq * 8 + 4);
    *(float4*)(kse1)     = *(const float4*)(ks + 32 + lq * 8);
    *(float4*)(kse1 + 4) = *(const float4*)(ks + 32 + lq * 8 + 4);

    #pragma unroll
    for (int t = 0; t < 2; ++t) {
        const int mt = u * 2 + t;
        if (mt >= 49) break;
        const size_t m0 = (size_t)b * 3136 + (size_t)mt * 64 + w * 16;

        const __hip_bfloat16* qrow = qkv + (m0 + l15) * 2304 + h * 64;
        bf16x8 aq0 = *(const bf16x8*)(qrow + lq * 8);
        bf16x8 aq1 = *(const bf16x8*)(qrow + 32 + lq * 8);

        float zp = 0.0f;
        #pragma unroll
        for (int j = 0; j < 8; ++j)
            zp += b2f(aq0[j]) * kse[j] + b2f(aq1[j]) * kse1[j];
        zp += __shfl_xor(zp, 16);
        zp += __shfl_xor(zp, 32);
        const float zr = 1.0f / (zp + EPS_Z);   // lane i<16 holds z-recip for row i

        f32x4 acc[4] = {};
        #pragma unroll
        for (int j = 0; j < 4; ++j) {
            acc[j] = __builtin_amdgcn_mfma_f32_16x16x32_bf16(aq0, b0[j], acc[j], 0, 0, 0);
            acc[j] = __builtin_amdgcn_mfma_f32_16x16x32_bf16(aq1, b1[j], acc[j], 0, 0, 0);
        }

        float zrow[4];
        #pragma unroll
        for (int r = 0; r < 4; ++r) zrow[r] = __shfl(zr, lq * 4 + r);

        #pragma unroll
        for (int j = 0; j < 4; ++j) {
            const int col = j * 16 + l15;
            #pragma unroll
            for (int r = 0; r < 4; ++r) {
                const int row = lq * 4 + r;
                att[(m0 + row) * 768 + h * 64 + col] = __float2bfloat16(acc[j][r] * zrow[r]);
            }
        }
    }
}

extern "C" void kernel_launch(void* const* d_in, const int* in_sizes, int n_in,
                              void* d_out, int out_size, void* d_ws, size_t ws_size,
                              hipStream_t stream)
{
    const float* x      = (const float*)d_in[0];   // [25088, 768]
    const float* W_qkv  = (const float*)d_in[1];   // [2304, 768]
    const float* W_proj = (const float*)d_in[2];   // [768, 768]
    const float* b_proj = (const float*)d_in[3];   // [768]
    float* out = (float*)d_out;

    const int M = 25088, K = 768, N1 = 2304, N2 = 768;
    const int SPLIT = 7;

    __hip_bfloat16* qkv = (__hip_bfloat16*)d_ws;            // M*N1
    __hip_bfloat16* xb  = qkv + (size_t)M * N1;             // M*K
    __hip_bfloat16* wqb = xb + (size_t)M * K;               // N1*K
    __hip_bfloat16* wpb = wqb + (size_t)N1 * K;             // N2*K
    float* kvp   = (float*)(wpb + (size_t)N2 * K);          // 7*96*4096 fp32 partials
    float* ksump = kvp + (size_t)SPLIT * 96 * 4096;         // 7*96*64 fp32 partials
    float* ksum  = ksump + (size_t)SPLIT * 96 * 64;         // 96*64 fp32
    __hip_bfloat16* kvb = (__hip_bfloat16*)(ksum + 96 * 64);// 96*4096 bf16
    __hip_bfloat16* att = xb;                               // alias: M*N2 <= M*K

    const int CVT_TOT = (M * K + N1 * K + N2 * K) / 4;
    cvt_all<<<(CVT_TOT + 255) / 256, 256, 0, stream>>>(x, W_qkv, W_proj, xb, wqb, wpb);

    gemm_bt<1, __hip_bfloat16><<<(M / 128) * (N1 / 128), 256, 0, stream>>>(
        xb, wqb, qkv, nullptr, K, N1, N1 / 128);
    kv_mfma_kernel<<<96 * SPLIT, 256, 0, stream>>>(qkv, kvp, ksump);
    kv_reduce<<<96, 256, 0, stream>>>(kvp, ksump, kvb, ksum);
    attn_mfma2<<<96 * 25, 256, 0, stream>>>(qkv, kvb, ksum, att);
    gemm_bt<2, float><<<(M / 128) * (N2 / 128), 256, 0, stream>>>(
        att, wpb, out, b_proj, K, N2, N2 / 128);
}